// Round 3
// baseline (461.378 us; speedup 1.0000x reference)
//
#include <hip/hip_runtime.h>

// Problem constants (fixed by setup_inputs): B=32, L=1024, K=64, N=8
namespace {
constexpr int Bb = 32, Ll = 1024, Kk = 64, Nn = 8;
constexpr int BLK = Bb * Ll * Kk;                      // 2,097,152 (b,l,k) elements
constexpr long long HFLOATS = (long long)BLK * Nn * 2; // 33,554,432 floats in H
constexpr int CH = 16;                                  // avg-reduction chunks per b
constexpr int LCH = Ll / CH;                            // 64 l's per chunk

// Output layout (flat concatenation in reference return order)
constexpr long long OFF_VQ  = 0;                         // v_q: BLK*2
constexpr long long OFF_HQ  = (long long)BLK * 2;        // H_q: BLK*16
constexpr long long OFF_EBD = OFF_HQ + HFLOATS;          // expected_bits_demod: BLK
constexpr long long OFF_EBC = OFF_EBD + BLK;             // expected_bits_channel: BLK
constexpr long long OFF_WD  = OFF_EBC + BLK;             // w_demod: BLK*3
constexpr long long OFF_WC  = OFF_WD + (long long)BLK*3; // w_channel: BLK*3
} // namespace

// forward of _lsq with precomputed reciprocal: round(clip(x*inv, Qn, Qp)) * s
__device__ __forceinline__ float lsq_i(float x, float inv, float s, float Qn, float Qp) {
    float xc = fminf(fmaxf(x * inv, Qn), Qp);
    return rintf(xc) * s;   // rintf = round-half-even, matches jnp.round
}

// w = hard_onehot(argmax(z)) + y - stopgrad(y), computed literally as (hard + y) - y.
// __expf + single-reciprocal softmax: deviations ~1e-7 in w, threshold is 1.28.
__device__ __forceinline__ void hard_gumbel(float z0, float z1, float z2, float w[3]) {
    int arg = 0; float m = z0;
    if (z1 > m) { m = z1; arg = 1; }   // strict > : first-occurrence tie-break = jnp.argmax
    if (z2 > m) { m = z2; arg = 2; }
    float e0 = __expf(z0 - m), e1 = __expf(z1 - m), e2 = __expf(z2 - m);
    float r  = 1.0f / (e0 + e1 + e2);
    float y0 = e0 * r, y1 = e1 * r, y2 = e2 * r;
    w[0] = ((arg == 0 ? 1.0f : 0.0f) + y0) - y0;
    w[1] = ((arg == 1 ? 1.0f : 0.0f) + y1) - y1;
    w[2] = ((arg == 2 ? 1.0f : 0.0f) + y2) - y2;
}

// ---------------------------------------------------------------------------
// Kernel 1: chunked h_power sums for avg.  partial[b][c][k] = sum_{l in chunk c}
// (f32)(f64 sum_{n,cx} H^2), accumulated in f64, deterministic order.
// grid = Bb*CH = 512 blocks x 256 threads; float4 loads cover a k-pair.
__global__ __launch_bounds__(256) void hpa_kernel(const float* __restrict__ H,
                                                  double* __restrict__ partial) {
    int blk = blockIdx.x;            // b*CH + c
    int b   = blk >> 4;
    int c   = blk & (CH - 1);
    int t   = threadIdx.x;
    int kp  = t & 31;                // k-pair index (k = 2*kp, 2*kp+1)
    int ls  = t >> 5;                // 8 l-lanes
    const float4* Hf = (const float4*)H;   // layout: [(bl*Nn + n)*32 + kp]
    double acc0 = 0.0, acc1 = 0.0;
    int l0 = c * LCH + ls;
    for (int i = 0; i < LCH / 8; ++i) {              // 8 l's per thread, stride 8
        int l = l0 + i * 8;
        const float4* Hb = Hf + (long long)(b * Ll + l) * (Nn * 32) + kp;
        double e0 = 0.0, e1 = 0.0;
        #pragma unroll
        for (int n = 0; n < Nn; ++n) {
            float4 h = Hb[n * 32];
            e0 += (double)(h.x * h.x);   // f32-rounded squares (match np H*H)
            e0 += (double)(h.y * h.y);
            e1 += (double)(h.z * h.z);
            e1 += (double)(h.w * h.w);
        }
        acc0 += (double)(float)e0;       // hp value f32-rounded exactly as np sees it
        acc1 += (double)(float)e1;
    }
    __shared__ double sh[2][256];
    sh[0][t] = acc0;
    sh[1][t] = acc1;
    __syncthreads();
    if (t < 64) {
        int kp2 = t & 31, sel = t >> 5;
        double s = 0.0;
        #pragma unroll
        for (int l2 = 0; l2 < 8; ++l2) s += sh[sel][l2 * 32 + kp2];
        partial[(long long)blk * 64 + 2 * kp2 + sel] = s;
    }
}

// ---------------------------------------------------------------------------
// Kernel 2: everything else, fused — TWO elements (a k-pair, same b,l) per thread.
// float4 H/v/v_q/H_q I/O, paired MLP for v_pk_fma formation, H re-loaded
// (L2/L3-warm) for the H_q epilogue to keep VGPRs ~148 (3 waves/SIMD).
__global__ __launch_bounds__(256) void fused_kernel(
    const float* __restrict__ v,  const float* __restrict__ snr,
    const float* __restrict__ gd, const float* __restrict__ gc,
    const float* __restrict__ W1, const float* __restrict__ b1,
    const float* __restrict__ W2, const float* __restrict__ b2,
    const float* __restrict__ Wd, const float* __restrict__ bd,
    const float* __restrict__ Wc, const float* __restrict__ bc,
    const float* __restrict__ ps2d, const float* __restrict__ ps4d,
    const float* __restrict__ ps2c, const float* __restrict__ ps4c,
    const double* __restrict__ partial,
    const float* __restrict__ H,
    float* __restrict__ out) {
    int t  = blockIdx.x * 256 + threadIdx.x;   // pair index in [0, BLK/2)
    int b  = t >> 15;                          // L*K/2 = 32768 per b
    int kp = t & 31;                           // k = 2*kp (elem a), 2*kp+1 (elem b)
    int bl = t >> 5;                           // b*L + l

    // ---- h_power for both elements (loads consumed immediately; regs freed)
    const float4* Hf = (const float4*)H + (long long)bl * (Nn * 32) + kp;
    double e0 = 0.0, e1 = 0.0;
    #pragma unroll
    for (int n = 0; n < Nn; ++n) {
        float4 h = Hf[n * 32];
        e0 += (double)(h.x * h.x);
        e0 += (double)(h.y * h.y);
        e1 += (double)(h.z * h.z);
        e1 += (double)(h.w * h.w);
    }
    float p3a = (float)e0, p3b = (float)e1;

    // ---- avg finalize: 16 f64 chunk partials per k, fixed order, /1024
    const double2* pb = (const double2*)(partial + (long long)b * (CH * 64)) + kp;
    double s0 = 0.0, s1 = 0.0;
    #pragma unroll
    for (int c = 0; c < CH; ++c) { double2 p = pb[c * 32]; s0 += p.x; s1 += p.y; }
    float p4a = (float)(s0 * (1.0 / 1024.0));
    float p4b = (float)(s1 * (1.0 / 1024.0));

    float4 vv = ((const float4*)v)[t];          // v for elem a (x,y) and b (z,w)
    float2 sn = ((const float2*)snr)[t];
    float p0a = vv.x, p1a = vv.y, p2a = sn.x;
    float p0b = vv.z, p1b = vv.w, p2b = sn.y;

    const float2* gdp = (const float2*)gd + (long long)t * 3;
    const float2* gcp = (const float2*)gc + (long long)t * 3;
    float2 gd0 = gdp[0], gd1 = gdp[1], gd2 = gdp[2];
    float2 gc0 = gcp[0], gc1 = gcp[1], gc2 = gcp[2];

    // ---- layer 1: 5 -> 32, relu, both elements interleaved
    float2 h1[32];
    #pragma unroll
    for (int i = 0; i < 32; ++i) {
        float w0 = W1[i], w1 = W1[32+i], w2 = W1[64+i], w3 = W1[96+i], w4 = W1[128+i];
        float aa = b1[i], ab = b1[i];
        aa = fmaf(p0a, w0, aa);  ab = fmaf(p0b, w0, ab);
        aa = fmaf(p1a, w1, aa);  ab = fmaf(p1b, w1, ab);
        aa = fmaf(p2a, w2, aa);  ab = fmaf(p2b, w2, ab);
        aa = fmaf(p3a, w3, aa);  ab = fmaf(p3b, w3, ab);
        aa = fmaf(p4a, w4, aa);  ab = fmaf(p4b, w4, ab);
        h1[i].x = fmaxf(aa, 0.0f);
        h1[i].y = fmaxf(ab, 0.0f);
    }
    // ---- layer 2: 32 -> 32, relu
    float2 h2[32];
    #pragma unroll
    for (int i = 0; i < 32; ++i) { h2[i].x = b2[i]; h2[i].y = b2[i]; }
    #pragma unroll
    for (int j = 0; j < 32; ++j) {
        float2 hj = h1[j];
        #pragma unroll
        for (int i = 0; i < 32; ++i) {
            float w = W2[j * 32 + i];
            h2[i].x = fmaf(hj.x, w, h2[i].x);
            h2[i].y = fmaf(hj.y, w, h2[i].y);
        }
    }
    #pragma unroll
    for (int i = 0; i < 32; ++i) { h2[i].x = fmaxf(h2[i].x, 0.0f); h2[i].y = fmaxf(h2[i].y, 0.0f); }
    // ---- heads: 32 -> 3 (demod) and 32 -> 3 (channel), both elements
    float2 ld0 = {bd[0], bd[0]}, ld1 = {bd[1], bd[1]}, ld2 = {bd[2], bd[2]};
    float2 lc0 = {bc[0], bc[0]}, lc1 = {bc[1], bc[1]}, lc2 = {bc[2], bc[2]};
    #pragma unroll
    for (int j = 0; j < 32; ++j) {
        float2 hj = h2[j];
        float wd0 = Wd[j*3+0], wd1 = Wd[j*3+1], wd2 = Wd[j*3+2];
        float wc0 = Wc[j*3+0], wc1 = Wc[j*3+1], wc2 = Wc[j*3+2];
        ld0.x = fmaf(hj.x, wd0, ld0.x);  ld0.y = fmaf(hj.y, wd0, ld0.y);
        ld1.x = fmaf(hj.x, wd1, ld1.x);  ld1.y = fmaf(hj.y, wd1, ld1.y);
        ld2.x = fmaf(hj.x, wd2, ld2.x);  ld2.y = fmaf(hj.y, wd2, ld2.y);
        lc0.x = fmaf(hj.x, wc0, lc0.x);  lc0.y = fmaf(hj.y, wc0, lc0.y);
        lc1.x = fmaf(hj.x, wc1, lc1.x);  lc1.y = fmaf(hj.y, wc1, lc1.y);
        lc2.x = fmaf(hj.x, wc2, lc2.x);  lc2.y = fmaf(hj.y, wc2, lc2.y);
    }

    // gumbel noise layout: elem a -> gd0.x,gd0.y,gd1.x ; elem b -> gd1.y,gd2.x,gd2.y
    float wdA[3], wdB[3], wcA[3], wcB[3];
    hard_gumbel(ld0.x + gd0.x, ld1.x + gd0.y, ld2.x + gd1.x, wdA);
    hard_gumbel(ld0.y + gd1.y, ld1.y + gd2.x, ld2.y + gd2.y, wdB);
    hard_gumbel(lc0.x + gc0.x, lc1.x + gc0.y, lc2.x + gc1.x, wcA);
    hard_gumbel(lc0.y + gc1.y, lc1.y + gc2.x, lc2.y + gc2.y, wcB);

    // ---- scales + reciprocals (s=0.5 exact; s=0.1 wobble <= one step << 1.28)
    float s2d = *ps2d, s4d = *ps4d, s2c = *ps2c, s4c = *ps4c;
    float i2d = 1.0f / s2d, i4d = 1.0f / s4d, i2c = 1.0f / s2c, i4c = 1.0f / s4c;

    // ---- v_q (float4 store covers both elements)
    float4 q;
    q.x = wdA[1] * lsq_i(p0a, i2d, s2d, -2.0f, 1.0f) + wdA[2] * lsq_i(p0a, i4d, s4d, -8.0f, 7.0f);
    q.y = wdA[1] * lsq_i(p1a, i2d, s2d, -2.0f, 1.0f) + wdA[2] * lsq_i(p1a, i4d, s4d, -8.0f, 7.0f);
    q.z = wdB[1] * lsq_i(p0b, i2d, s2d, -2.0f, 1.0f) + wdB[2] * lsq_i(p0b, i4d, s4d, -8.0f, 7.0f);
    q.w = wdB[1] * lsq_i(p1b, i2d, s2d, -2.0f, 1.0f) + wdB[2] * lsq_i(p1b, i4d, s4d, -8.0f, 7.0f);
    ((float4*)(out + OFF_VQ))[t] = q;

    // ---- bits + gate outputs (all vectorized pairs)
    ((float2*)(out + OFF_EBD))[t] = make_float2(wdA[1] * 4.0f + wdA[2] * 8.0f,
                                                wdB[1] * 4.0f + wdB[2] * 8.0f);
    ((float2*)(out + OFF_EBC))[t] = make_float2(wcA[1] * 32.0f + wcA[2] * 64.0f,
                                                wcB[1] * 32.0f + wcB[2] * 64.0f);
    float2* wdp = (float2*)(out + OFF_WD) + (long long)t * 3;
    wdp[0] = make_float2(wdA[0], wdA[1]);
    wdp[1] = make_float2(wdA[2], wdB[0]);
    wdp[2] = make_float2(wdB[1], wdB[2]);
    float2* wcp = (float2*)(out + OFF_WC) + (long long)t * 3;
    wcp[0] = make_float2(wcA[0], wcA[1]);
    wcp[1] = make_float2(wcA[2], wcB[0]);
    wcp[2] = make_float2(wcB[1], wcB[2]);

    // ---- H_q epilogue: re-load H (L2/L3-warm; keeps MLP-phase VGPRs low)
    float w1a = wcA[1], w2a = wcA[2], w1b = wcB[1], w2b = wcB[2];
    float4* oq = (float4*)(out + OFF_HQ) + (long long)bl * (Nn * 32) + kp;
    #pragma unroll
    for (int n = 0; n < Nn; ++n) {
        float4 h = Hf[n * 32];
        float4 o;
        o.x = w1a * lsq_i(h.x, i2c, s2c, -2.0f, 1.0f) + w2a * lsq_i(h.x, i4c, s4c, -8.0f, 7.0f);
        o.y = w1a * lsq_i(h.y, i2c, s2c, -2.0f, 1.0f) + w2a * lsq_i(h.y, i4c, s4c, -8.0f, 7.0f);
        o.z = w1b * lsq_i(h.z, i2c, s2c, -2.0f, 1.0f) + w2b * lsq_i(h.z, i4c, s4c, -8.0f, 7.0f);
        o.w = w1b * lsq_i(h.w, i2c, s2c, -2.0f, 1.0f) + w2b * lsq_i(h.w, i4c, s4c, -8.0f, 7.0f);
        oq[n * 32] = o;
    }
}

// ---------------------------------------------------------------------------
extern "C" void kernel_launch(void* const* d_in, const int* in_sizes, int n_in,
                              void* d_out, int out_size, void* d_ws, size_t ws_size,
                              hipStream_t stream) {
    const float* v    = (const float*)d_in[0];
    const float* H    = (const float*)d_in[1];
    const float* snr  = (const float*)d_in[2];
    const float* gd   = (const float*)d_in[3];
    const float* gc   = (const float*)d_in[4];
    const float* W1   = (const float*)d_in[5];
    const float* b1   = (const float*)d_in[6];
    const float* W2   = (const float*)d_in[7];
    const float* b2   = (const float*)d_in[8];
    const float* Wd   = (const float*)d_in[9];
    const float* bd   = (const float*)d_in[10];
    const float* Wc   = (const float*)d_in[11];
    const float* bc   = (const float*)d_in[12];
    const float* s2d  = (const float*)d_in[13];
    const float* s4d  = (const float*)d_in[14];
    const float* s2c  = (const float*)d_in[15];
    const float* s4c  = (const float*)d_in[16];

    float* out = (float*)d_out;
    double* partial = (double*)d_ws;   // Bb*CH*64 doubles = 256 KB, fully written by k1

    hpa_kernel<<<Bb * CH, 256, 0, stream>>>(H, partial);
    fused_kernel<<<BLK / 2 / 256, 256, 0, stream>>>(v, snr, gd, gc, W1, b1, W2, b2,
                                                    Wd, bd, Wc, bc, s2d, s4d, s2c, s4c,
                                                    partial, H, out);
}